// Round 8
// baseline (732.302 us; speedup 1.0000x reference)
//
#include <hip/hip_runtime.h>

typedef int i4  __attribute__((ext_vector_type(4)));
typedef int i4u __attribute__((ext_vector_type(4), aligned(4)));   // 4B-aligned 16B ld

#define THREADS 256
#define WAVES_PB 4
#define K1_BLOCKS 4096       // pack: chunks of 1024 src elems, max 32768
#define K1_ITERS 2
#define SWEEP_BLOCKS 512     // 2048 waves, long contiguous spans (fill regime)
#define PK_OFF 256           // packed buffer offset within ws, in ints
#define WS_NEED ((size_t)4 * (PK_OFF + 32768u * 1024u))   // ~134 MB

// ws layout (uint32):
//  [0..8]   offE : output elem prefix, offE[b] = sum_{j<b} 16*s_j^2
//  [9..17]  csum : 1k-chunk prefix over s^2, csum[b] = sum_{j<b} ceil(s_j^2/1024)
//  [18..25] s[b]   [26..33] s2[b]   [34..41] inv_s[b] (float bits)
//  [PK_OFF..] packed bools as int32, batch b at csum[b]*1024
__global__ void setup_offsets_kernel(const int* __restrict__ seq,
                                     unsigned int* __restrict__ ws) {
    if (threadIdx.x == 0 && blockIdx.x == 0) {
        unsigned int oE = 0, cs = 0;
        ws[0] = 0u; ws[9] = 0u;
        for (int b = 0; b < 8; ++b) {
            unsigned int s  = (unsigned int)seq[b];
            unsigned int s2 = s * s;
            oE += s2 << 4;
            cs += (s2 + 1023u) >> 10;
            ws[1 + b]  = oE;
            ws[10 + b] = cs;
            ws[18 + b] = s;
            ws[26 + b] = s2;
            ((float*)ws)[34 + b] = 1.0f / (float)s;
        }
    }
}

// Phase 1: pack mask[b,:s,:s] > 0.5 into packed int32 (one copy, no heads).
__global__ void __launch_bounds__(THREADS)
pack_kernel(const float* __restrict__ mask, const unsigned int* __restrict__ ws,
            int* __restrict__ pk) {
    __shared__ unsigned int csum[9];
    __shared__ unsigned int slen[8];
    __shared__ unsigned int ssq[8];
    __shared__ float        sinv[8];
    int tx = threadIdx.x;
    if (tx < 9) csum[tx] = ws[9 + tx];
    if (tx < 8) {
        slen[tx] = ws[18 + tx];
        ssq[tx]  = ws[26 + tx];
        sinv[tx] = ((const float*)ws)[34 + tx];
    }
    __syncthreads();

    unsigned int nchunks     = csum[8];
    unsigned int total_waves = gridDim.x * WAVES_PB;
    unsigned int wave_id     = blockIdx.x * WAVES_PB + ((unsigned int)tx >> 6);
    unsigned int lane        = (unsigned int)tx & 63u;

#pragma unroll 1
    for (int it = 0; it < K1_ITERS; ++it) {
        unsigned int chunk = wave_id + (unsigned int)it * total_waves;
        if (chunk >= nchunks) break;

        unsigned int b = 0;
#pragma unroll
        for (int j = 1; j < 8; ++j) b += (chunk >= csum[j]) ? 1u : 0u;

        unsigned int s   = slen[b];
        unsigned int s2  = ssq[b];
        float        inv = sinv[b];
        unsigned int p0  = (chunk - csum[b]) << 10;
        unsigned int pb  = csum[b] << 10;          // packed base
        const float* mb  = mask + ((size_t)b << 22);

#pragma unroll
        for (int sub = 0; sub < 4; ++sub) {
            unsigned int p = p0 + ((unsigned int)sub << 8) + (lane << 2);
            if (p + 4u <= s2) {
                unsigned int row = (unsigned int)((float)p * inv);
                int col = (int)p - (int)(row * s);
                if (col < 0)            { row -= 1u; col += (int)s; }
                else if (col >= (int)s) { row += 1u; col -= (int)s; }
                unsigned int r0 = row;  int c0 = col;
                float v0 = mb[(size_t)r0 * 2048u + (unsigned int)c0];
                c0++; if (c0 == (int)s) { c0 = 0; r0++; }
                float v1 = mb[(size_t)r0 * 2048u + (unsigned int)c0];
                c0++; if (c0 == (int)s) { c0 = 0; r0++; }
                float v2 = mb[(size_t)r0 * 2048u + (unsigned int)c0];
                c0++; if (c0 == (int)s) { c0 = 0; r0++; }
                float v3 = mb[(size_t)r0 * 2048u + (unsigned int)c0];
                i4 o = (i4){(v0 > 0.5f) ? 1 : 0, (v1 > 0.5f) ? 1 : 0,
                            (v2 > 0.5f) ? 1 : 0, (v3 > 0.5f) ? 1 : 0};
                *(i4*)(pk + pb + p) = o;
            } else {
#pragma unroll
                for (int j = 0; j < 4; ++j) {
                    unsigned int pp = p + (unsigned int)j;
                    if (pp >= s2) continue;
                    unsigned int row = (unsigned int)((float)pp * inv);
                    int col = (int)pp - (int)(row * s);
                    if (col < 0)            { row -= 1u; col += (int)s; }
                    else if (col >= (int)s) { row += 1u; col -= (int)s; }
                    float v = mb[(size_t)row * 2048u + (unsigned int)col];
                    pk[pb + pp] = (v > 0.5f) ? 1 : 0;
                }
            }
        }
    }
}

// Phase 2: SWEEP. Block owns a contiguous output partition; waves stride 4KB
// chunks inside it. Per head-segment the src delta is constant -> pure memcpy.
__global__ void __launch_bounds__(THREADS)
sweep_kernel(const unsigned int* __restrict__ ws, const int* __restrict__ pk,
             int* __restrict__ out) {
    __shared__ unsigned int offE[9];
    __shared__ unsigned int csum[9];
    __shared__ unsigned int ssq[8];
    int tx = threadIdx.x;
    if (tx < 9) { offE[tx] = ws[tx]; csum[tx] = ws[9 + tx]; }
    if (tx < 8) ssq[tx] = ws[26 + tx];
    __syncthreads();

    unsigned int Ntot = offE[8];
    // per-block partition, rounded to whole 4KB chunks (16384 elems granule)
    unsigned int R = ((Ntot + (unsigned int)SWEEP_BLOCKS - 1u) / (unsigned int)SWEEP_BLOCKS
                      + 16383u) & ~16383u;
    unsigned int blk_base = blockIdx.x * R;
    if (blk_base >= Ntot) return;
    unsigned int blk_end = blk_base + R;
    if (blk_end > Ntot) blk_end = Ntot;

    unsigned int wid  = (unsigned int)tx >> 6;
    unsigned int lane = (unsigned int)tx & 63u;

#pragma unroll 1
    for (unsigned int c = wid; ; c += WAVES_PB) {
        unsigned int x  = blk_base + (c << 10);
        if (x >= blk_end) break;
        unsigned int xe = x + 1024u;
        if (xe > blk_end) xe = blk_end;

#pragma unroll 1
        while (x < xe) {
            // locate batch / head segment containing x (wave-uniform)
            unsigned int b = 0;
#pragma unroll
            for (int j = 1; j < 8; ++j) b += (x >= offE[j]) ? 1u : 0u;
            unsigned int s2    = ssq[b];
            unsigned int local = x - offE[b];
            unsigned int h     = local / s2;               // 32-bit udiv, per segment
            unsigned int hb    = offE[b] + h * s2;
            unsigned int send  = hb + s2;
            if (send > xe) send = xe;
            if (send <= x) break;                          // defensive: never wedge
            int delta = (int)(csum[b] << 10) - (int)hb;    // src = pk[e + delta]

            if (send == x + 1024u) {
                // full aligned 4KB chunk (x provably 1024-aligned here):
                // 4 hot loads, 4 dense aligned stores
                unsigned int q0 = (x >> 2) + lane;
                i4 a0 = *(const i4u*)(pk + (int)(q0 << 2) + delta);
                i4 a1 = *(const i4u*)(pk + (int)((q0 + 64u) << 2) + delta);
                i4 a2 = *(const i4u*)(pk + (int)((q0 + 128u) << 2) + delta);
                i4 a3 = *(const i4u*)(pk + (int)((q0 + 192u) << 2) + delta);
                *(i4*)(out + ((q0) << 2))        = a0;
                *(i4*)(out + ((q0 + 64u) << 2))  = a1;
                *(i4*)(out + ((q0 + 128u) << 2)) = a2;
                *(i4*)(out + ((q0 + 192u) << 2)) = a3;
            } else {
                // general segment [x, send): aligned quads + <=3 edge scalars
                unsigned int qs = (x + 3u) >> 2;
                unsigned int qe = send >> 2;
#pragma unroll 1
                for (unsigned int q = qs + lane; q < qe; q += 64u) {
                    i4 v = *(const i4u*)(pk + (int)(q << 2) + delta);
                    *(i4*)(out + (q << 2)) = v;
                }
                if (lane < 3u) {
                    unsigned int e = x + lane;               // leading scalars
                    if (e < send && e < (qs << 2)) out[e] = pk[(int)e + delta];
                    unsigned int e2 = (qe << 2) + lane;      // trailing scalars
                    if (e2 >= x && e2 < send) out[e2] = pk[(int)e2 + delta];
                }
            }
            x = send;
        }
    }
}

// ---------------- fallback path (R4, best verified) ----------------

#define STORE_SHIFT(VV, SIG) do {                                              \
    *(i4*)(out + offh + 0   + (SIG)) = VV[0];                                  \
    *(i4*)(out + offh + 256 + (SIG)) = VV[1];                                  \
    *(i4*)(out + offh + 512 + (SIG)) = VV[2];                                  \
    if (lane < 63u) *(i4*)(out + offh + 768 + (SIG)) = VV[3];                  \
    if (lane == 0u) {                                                          \
        out[habase] = o[0].x;                                                  \
        if ((SIG) >= 2) out[habase + 1] = o[0].y;                              \
        if ((SIG) == 3) out[habase + 2] = o[0].z;                              \
    }                                                                          \
    if (lane == 63u) {                                                         \
        if ((SIG) == 1) out[habase + 1021] = o[3].y;                           \
        if ((SIG) <= 2) out[habase + 1022] = o[3].z;                           \
        out[habase + 1023] = o[3].w;                                           \
    }                                                                          \
} while (0)

__global__ void __launch_bounds__(THREADS)
unpad_mask_kernel_fb(const float* __restrict__ mask,
                     const unsigned int* __restrict__ ws,
                     int* __restrict__ out) {
    __shared__ unsigned int off16[9];
    __shared__ unsigned int csum[9];
    __shared__ unsigned int slen[8];
    __shared__ unsigned int ssq[8];
    __shared__ float        sinv[8];

    int tx = threadIdx.x;
    if (tx < 9) { off16[tx] = ws[tx]; csum[tx] = ws[9 + tx]; }
    if (tx < 8) {
        slen[tx] = ws[18 + tx];
        ssq[tx]  = ws[26 + tx];
        sinv[tx] = ((const float*)ws)[34 + tx];
    }
    __syncthreads();

    unsigned int nchunks     = csum[8];
    unsigned int total_waves = gridDim.x * WAVES_PB;
    unsigned int wave_id     = blockIdx.x * WAVES_PB + ((unsigned int)tx >> 6);
    unsigned int lane        = (unsigned int)tx & 63u;

#pragma unroll 1
    for (int it = 0; it < K1_ITERS; ++it) {
        unsigned int chunk = wave_id + (unsigned int)it * total_waves;
        if (chunk >= nchunks) break;

        unsigned int b = 0;
#pragma unroll
        for (int j = 1; j < 8; ++j) b += (chunk >= csum[j]) ? 1u : 0u;

        unsigned int s    = slen[b];
        unsigned int s2   = ssq[b];
        float        inv  = sinv[b];
        unsigned int p0   = (chunk - csum[b]) << 10;
        unsigned int base = off16[b];
        const float* mb   = mask + ((size_t)b << 22);

        if (s2 - p0 >= 1024u) {
            unsigned int q0 = p0 + (lane << 2);
            i4 o[4];
#pragma unroll
            for (int sub = 0; sub < 4; ++sub) {
                unsigned int q   = q0 + ((unsigned int)sub << 8);
                unsigned int row = (unsigned int)((float)q * inv);
                int col = (int)q - (int)(row * s);
                if (col < 0)            { row -= 1u; col += (int)s; }
                else if (col >= (int)s) { row += 1u; col -= (int)s; }
                unsigned int r0 = row;  int c0 = col;
                float v0 = mb[(size_t)r0 * 2048u + (unsigned int)c0];
                c0++; if (c0 == (int)s) { c0 = 0; r0++; }
                float v1 = mb[(size_t)r0 * 2048u + (unsigned int)c0];
                c0++; if (c0 == (int)s) { c0 = 0; r0++; }
                float v2 = mb[(size_t)r0 * 2048u + (unsigned int)c0];
                c0++; if (c0 == (int)s) { c0 = 0; r0++; }
                float v3 = mb[(size_t)r0 * 2048u + (unsigned int)c0];
                o[sub] = (i4){(v0 > 0.5f) ? 1 : 0, (v1 > 0.5f) ? 1 : 0,
                              (v2 > 0.5f) ? 1 : 0, (v3 > 0.5f) ? 1 : 0};
            }

            if ((s & 1u) == 0u) {
                unsigned int off = base + q0;
#pragma unroll
                for (int h = 0; h < 16; ++h) {
                    *(i4*)(out + off)       = o[0];
                    *(i4*)(out + off + 256) = o[1];
                    *(i4*)(out + off + 512) = o[2];
                    *(i4*)(out + off + 768) = o[3];
                    off += s2;
                }
            } else {
                int src = ((int)lane + 1) & 63;
                int sel = (lane == 0u) ? 1 : 0;
                int e0x = sel ? o[1].x : o[0].x;
                int e0y = sel ? o[1].y : o[0].y;
                int e0z = sel ? o[1].z : o[0].z;
                int e1x = sel ? o[2].x : o[1].x;
                int e1y = sel ? o[2].y : o[1].y;
                int e1z = sel ? o[2].z : o[1].z;
                int e2x = sel ? o[3].x : o[2].x;
                int e2y = sel ? o[3].y : o[2].y;
                int e2z = sel ? o[3].z : o[2].z;
                int n0x = __shfl(e0x, src, 64), n0y = __shfl(e0y, src, 64), n0z = __shfl(e0z, src, 64);
                int n1x = __shfl(e1x, src, 64), n1y = __shfl(e1y, src, 64), n1z = __shfl(e1z, src, 64);
                int n2x = __shfl(e2x, src, 64), n2y = __shfl(e2y, src, 64), n2z = __shfl(e2z, src, 64);
                int n3x = __shfl(o[3].x, src, 64), n3y = __shfl(o[3].y, src, 64), n3z = __shfl(o[3].z, src, 64);

                i4 v1[4], v2[4], v3[4];
                v1[0] = (i4){o[0].y, o[0].z, o[0].w, n0x};
                v1[1] = (i4){o[1].y, o[1].z, o[1].w, n1x};
                v1[2] = (i4){o[2].y, o[2].z, o[2].w, n2x};
                v1[3] = (i4){o[3].y, o[3].z, o[3].w, n3x};
                v2[0] = (i4){o[0].z, o[0].w, n0x, n0y};
                v2[1] = (i4){o[1].z, o[1].w, n1x, n1y};
                v2[2] = (i4){o[2].z, o[2].w, n2x, n2y};
                v2[3] = (i4){o[3].z, o[3].w, n3x, n3y};
                v3[0] = (i4){o[0].w, n0x, n0y, n0z};
                v3[1] = (i4){o[1].w, n1x, n1y, n1z};
                v3[2] = (i4){o[2].w, n2x, n2y, n2z};
                v3[3] = (i4){o[3].w, n3x, n3y, n3z};

                unsigned int habase = base + p0;
#pragma unroll
                for (int h = 0; h < 16; ++h) {
                    unsigned int offh = habase + (lane << 2);
                    const int r0c = h & 3;
                    if (r0c == 0) {
                        *(i4*)(out + offh)       = o[0];
                        *(i4*)(out + offh + 256) = o[1];
                        *(i4*)(out + offh + 512) = o[2];
                        *(i4*)(out + offh + 768) = o[3];
                    } else if (r0c == 1) {
                        STORE_SHIFT(v3, 3);
                    } else if (r0c == 2) {
                        STORE_SHIFT(v2, 2);
                    } else {
                        STORE_SHIFT(v1, 1);
                    }
                    habase += s2;
                }
            }
        } else {
#pragma unroll 1
            for (int sub = 0; sub < 4; ++sub) {
                unsigned int sp0 = p0 + ((unsigned int)sub << 8);
                if (sp0 >= s2) break;
#pragma unroll
                for (int j = 0; j < 4; ++j) {
                    unsigned int p = sp0 + (lane << 2) + (unsigned int)j;
                    if (p >= s2) continue;
                    unsigned int row = (unsigned int)((float)p * inv);
                    int col = (int)p - (int)(row * s);
                    if (col < 0)            { row -= 1u; col += (int)s; }
                    else if (col >= (int)s) { row += 1u; col -= (int)s; }
                    float v = mb[(size_t)row * 2048u + (unsigned int)col];
                    int o = (v > 0.5f) ? 1 : 0;
                    unsigned int off = base + p;
#pragma unroll
                    for (int h = 0; h < 16; ++h) {
                        out[off] = o;
                        off += s2;
                    }
                }
            }
        }
    }
}

extern "C" void kernel_launch(void* const* d_in, const int* in_sizes, int n_in,
                              void* d_out, int out_size, void* d_ws, size_t ws_size,
                              hipStream_t stream) {
    const float*  mask = (const float*)d_in[0];
    const int*    seq  = (const int*)d_in[1];
    unsigned int* ws   = (unsigned int*)d_ws;
    int*          out  = (int*)d_out;

    setup_offsets_kernel<<<1, 64, 0, stream>>>(seq, ws);
    if (ws_size >= WS_NEED) {
        int* pk = (int*)ws + PK_OFF;
        pack_kernel<<<K1_BLOCKS, THREADS, 0, stream>>>(mask, ws, pk);
        sweep_kernel<<<SWEEP_BLOCKS, THREADS, 0, stream>>>(ws, pk, out);
    } else {
        unpad_mask_kernel_fb<<<K1_BLOCKS, THREADS, 0, stream>>>(mask, ws, out);
    }
}

// Round 9
// 660.527 us; speedup vs baseline: 1.1087x; 1.1087x over previous
//
#include <hip/hip_runtime.h>

typedef int i4 __attribute__((ext_vector_type(4)));
typedef int i2 __attribute__((ext_vector_type(2)));

#define THREADS 256
#define WAVES_PB 4      // 256 threads = 4 waves
#define ITERS 2         // strided chunks per wave
// chunk = 1024 src elems. worst case: 8 * ceil(2048^2/1024) = 32768
// capacity: 4096 blocks * 4 waves * 2 iters = 32768
#define MAX_BLOCKS 4096

// For odd-s heads with shift SIG = 4-(h&3):
//  - aligned i4 groups cover chunk elems [SIG, 1020+SIG); lane 63 skips k=3
//  - leading elems [0,SIG) scalar by lane 0; tail [1020+SIG,1024) by lane 63
#define STORE_SHIFT(VV, SIG) do {                                              \
    *(i4*)(out + offh + 0   + (SIG)) = VV[0];                                  \
    *(i4*)(out + offh + 256 + (SIG)) = VV[1];                                  \
    *(i4*)(out + offh + 512 + (SIG)) = VV[2];                                  \
    if (lane < 63u) *(i4*)(out + offh + 768 + (SIG)) = VV[3];                  \
    if (lane == 0u) {                                                          \
        out[habase] = o[0].x;                                                  \
        if ((SIG) >= 2) out[habase + 1] = o[0].y;                              \
        if ((SIG) == 3) out[habase + 2] = o[0].z;                              \
    }                                                                          \
    if (lane == 63u) {                                                         \
        if ((SIG) == 1) out[habase + 1021] = o[3].y;                           \
        if ((SIG) <= 2) out[habase + 1022] = o[3].z;                           \
        out[habase + 1023] = o[3].w;                                           \
    }                                                                          \
} while (0)

__global__ void __launch_bounds__(THREADS)
unpad_mask_kernel(const float* __restrict__ mask,     // fp16 promoted to f32 by harness
                  const int* __restrict__ seq,
                  int* __restrict__ out) {             // bool output as int32
    __shared__ unsigned int off16[9];   // output prefix: sum_{j<b} 16*s_j^2
    __shared__ unsigned int csum[9];    // chunk prefix:  sum_{j<b} ceil(s_j^2/1024)
    __shared__ unsigned int slen[8];
    __shared__ unsigned int ssq[8];
    __shared__ float        sinv[8];

    int tx = threadIdx.x;
    // fused setup: each block's thread 0 builds the table from seq (L2-hot)
    if (tx == 0) {
        unsigned int o16 = 0, cs = 0;
        off16[0] = 0u; csum[0] = 0u;
#pragma unroll
        for (int b = 0; b < 8; ++b) {
            unsigned int s  = (unsigned int)seq[b];
            unsigned int s2 = s * s;
            o16 += s2 << 4;
            cs  += (s2 + 1023u) >> 10;
            off16[b + 1] = o16;
            csum[b + 1]  = cs;
            slen[b] = s;
            ssq[b]  = s2;
            sinv[b] = 1.0f / (float)s;
        }
    }
    __syncthreads();

    unsigned int nchunks     = csum[8];
    unsigned int total_waves = gridDim.x * WAVES_PB;
    unsigned int wave_id     = blockIdx.x * WAVES_PB + ((unsigned int)tx >> 6);
    unsigned int lane        = (unsigned int)tx & 63u;

#pragma unroll 1
    for (int it = 0; it < ITERS; ++it) {
        unsigned int chunk = wave_id + (unsigned int)it * total_waves;
        if (chunk >= nchunks) break;

        // batch search over chunk prefix (monotone, wave-uniform)
        unsigned int b = 0;
#pragma unroll
        for (int j = 1; j < 8; ++j) b += (chunk >= csum[j]) ? 1u : 0u;

        unsigned int s    = slen[b];
        unsigned int s2   = ssq[b];
        float        inv  = sinv[b];
        unsigned int p0   = (chunk - csum[b]) << 10;   // batch-local, mult of 1024
        unsigned int base = off16[b];
        const float* mb   = mask + ((size_t)b << 22);

        if (s2 - p0 >= 1024u) {
            // ---- fast path: full chunk (s >= 32) ----
            unsigned int q0 = p0 + (lane << 2);
            i4 o[4];
#pragma unroll
            for (int sub = 0; sub < 4; ++sub) {
                unsigned int q   = q0 + ((unsigned int)sub << 8);
                unsigned int row = (unsigned int)((float)q * inv);
                int col = (int)q - (int)(row * s);
                if (col < 0)            { row -= 1u; col += (int)s; }
                else if (col >= (int)s) { row += 1u; col -= (int)s; }

                unsigned int r0 = row;  int c0 = col;
                float v0 = mb[(size_t)r0 * 2048u + (unsigned int)c0];
                c0++; if (c0 == (int)s) { c0 = 0; r0++; }
                float v1 = mb[(size_t)r0 * 2048u + (unsigned int)c0];
                c0++; if (c0 == (int)s) { c0 = 0; r0++; }
                float v2 = mb[(size_t)r0 * 2048u + (unsigned int)c0];
                c0++; if (c0 == (int)s) { c0 = 0; r0++; }
                float v3 = mb[(size_t)r0 * 2048u + (unsigned int)c0];

                o[sub] = (i4){(v0 > 0.5f) ? 1 : 0, (v1 > 0.5f) ? 1 : 0,
                              (v2 > 0.5f) ? 1 : 0, (v3 > 0.5f) ? 1 : 0};
            }

            if ((s & 1u) == 0u) {
                // ---- even s: all heads 16B-aligned ----
                unsigned int off = base + q0;
#pragma unroll
                for (int h = 0; h < 16; ++h) {
                    *(i4*)(out + off)       = o[0];
                    *(i4*)(out + off + 256) = o[1];
                    *(i4*)(out + off + 512) = o[2];
                    *(i4*)(out + off + 768) = o[3];
                    off += s2;
                }
            } else {
                // ---- odd s: rotation-aligned i4 stores (verified R4 logic) ----
                int src = ((int)lane + 1) & 63;
                int sel = (lane == 0u) ? 1 : 0;
                int e0x = sel ? o[1].x : o[0].x;
                int e0y = sel ? o[1].y : o[0].y;
                int e0z = sel ? o[1].z : o[0].z;
                int e1x = sel ? o[2].x : o[1].x;
                int e1y = sel ? o[2].y : o[1].y;
                int e1z = sel ? o[2].z : o[1].z;
                int e2x = sel ? o[3].x : o[2].x;
                int e2y = sel ? o[3].y : o[2].y;
                int e2z = sel ? o[3].z : o[2].z;
                int n0x = __shfl(e0x, src, 64), n0y = __shfl(e0y, src, 64), n0z = __shfl(e0z, src, 64);
                int n1x = __shfl(e1x, src, 64), n1y = __shfl(e1y, src, 64), n1z = __shfl(e1z, src, 64);
                int n2x = __shfl(e2x, src, 64), n2y = __shfl(e2y, src, 64), n2z = __shfl(e2z, src, 64);
                int n3x = __shfl(o[3].x, src, 64), n3y = __shfl(o[3].y, src, 64), n3z = __shfl(o[3].z, src, 64);

                i4 v1[4], v2[4], v3[4];
                v1[0] = (i4){o[0].y, o[0].z, o[0].w, n0x};
                v1[1] = (i4){o[1].y, o[1].z, o[1].w, n1x};
                v1[2] = (i4){o[2].y, o[2].z, o[2].w, n2x};
                v1[3] = (i4){o[3].y, o[3].z, o[3].w, n3x};
                v2[0] = (i4){o[0].z, o[0].w, n0x, n0y};
                v2[1] = (i4){o[1].z, o[1].w, n1x, n1y};
                v2[2] = (i4){o[2].z, o[2].w, n2x, n2y};
                v2[3] = (i4){o[3].z, o[3].w, n3x, n3y};
                v3[0] = (i4){o[0].w, n0x, n0y, n0z};
                v3[1] = (i4){o[1].w, n1x, n1y, n1z};
                v3[2] = (i4){o[2].w, n2x, n2y, n2z};
                v3[3] = (i4){o[3].w, n3x, n3y, n3z};

                unsigned int habase = base + p0;   // wave-uniform head base, += s2
#pragma unroll
                for (int h = 0; h < 16; ++h) {
                    unsigned int offh = habase + (lane << 2);
                    const int r0c = h & 3;         // compile-time under unroll
                    if (r0c == 0) {
                        *(i4*)(out + offh)       = o[0];
                        *(i4*)(out + offh + 256) = o[1];
                        *(i4*)(out + offh + 512) = o[2];
                        *(i4*)(out + offh + 768) = o[3];
                    } else if (r0c == 1) {
                        STORE_SHIFT(v3, 3);
                    } else if (r0c == 2) {
                        STORE_SHIFT(v2, 2);
                    } else {
                        STORE_SHIFT(v1, 1);
                    }
                    habase += s2;
                }
            }
        } else {
            // ---- fallback: partial tail chunk or tiny s ----
#pragma unroll 1
            for (int sub = 0; sub < 4; ++sub) {
                unsigned int sp0 = p0 + ((unsigned int)sub << 8);
                if (sp0 >= s2) break;

                if (s2 - sp0 >= 256u) {
                    unsigned int q   = sp0 + (lane << 2);
                    unsigned int row = (unsigned int)((float)q * inv);
                    int col = (int)q - (int)(row * s);
                    if (col < 0)            { row -= 1u; col += (int)s; }
                    else if (col >= (int)s) { row += 1u; col -= (int)s; }

                    unsigned int r0 = row;  int c0 = col;
                    float v0 = mb[(size_t)r0 * 2048u + (unsigned int)c0];
                    c0++; if (c0 == (int)s) { c0 = 0; r0++; }
                    float v1 = mb[(size_t)r0 * 2048u + (unsigned int)c0];
                    c0++; if (c0 == (int)s) { c0 = 0; r0++; }
                    float v2 = mb[(size_t)r0 * 2048u + (unsigned int)c0];
                    c0++; if (c0 == (int)s) { c0 = 0; r0++; }
                    float v3 = mb[(size_t)r0 * 2048u + (unsigned int)c0];

                    int o0 = (v0 > 0.5f) ? 1 : 0;
                    int o1 = (v1 > 0.5f) ? 1 : 0;
                    int o2 = (v2 > 0.5f) ? 1 : 0;
                    int o3 = (v3 > 0.5f) ? 1 : 0;
                    i4 o4  = (i4){o0, o1, o2, o3};
                    i2 o2a = (i2){o0, o1};
                    i2 o2b = (i2){o2, o3};

                    unsigned int off = base + q;
                    if ((s & 1u) == 0u) {
#pragma unroll
                        for (int h = 0; h < 16; ++h) {
                            *(i4*)(out + off) = o4;
                            off += s2;
                        }
                    } else {
#pragma unroll
                        for (int h = 0; h < 16; ++h) {
                            if ((h & 3) == 0) {
                                *(i4*)(out + off) = o4;
                            } else if ((h & 3) == 2) {
                                *(i2*)(out + off)     = o2a;
                                *(i2*)(out + off + 2) = o2b;
                            } else {
                                out[off]     = o0;
                                out[off + 1] = o1;
                                out[off + 2] = o2;
                                out[off + 3] = o3;
                            }
                            off += s2;
                        }
                    }
                } else {
                    // partial tail chunk or tiny s: per-element
#pragma unroll
                    for (int j = 0; j < 4; ++j) {
                        unsigned int p = sp0 + (lane << 2) + (unsigned int)j;
                        if (p >= s2) continue;
                        unsigned int row = (unsigned int)((float)p * inv);
                        int col = (int)p - (int)(row * s);
                        if (col < 0)            { row -= 1u; col += (int)s; }
                        else if (col >= (int)s) { row += 1u; col -= (int)s; }
                        float v = mb[(size_t)row * 2048u + (unsigned int)col];
                        int o = (v > 0.5f) ? 1 : 0;
                        unsigned int off = base + p;
#pragma unroll
                        for (int h = 0; h < 16; ++h) {
                            out[off] = o;
                            off += s2;
                        }
                    }
                }
            }
        }
    }
}

extern "C" void kernel_launch(void* const* d_in, const int* in_sizes, int n_in,
                              void* d_out, int out_size, void* d_ws, size_t ws_size,
                              hipStream_t stream) {
    const float* mask = (const float*)d_in[0];
    const int*   seq  = (const int*)d_in[1];
    int*         out  = (int*)d_out;
    (void)d_ws; (void)ws_size;

    unpad_mask_kernel<<<MAX_BLOCKS, THREADS, 0, stream>>>(mask, seq, out);
}